// Round 16
// baseline (72.658 us; speedup 1.0000x reference)
//
#include <hip/hip_runtime.h>
#include <hip/hip_fp16.h>

#define N_NODES 100000
#define N_EDGES 1000000
#define D_FEAT  64

// Binning: 64 consecutive dst nodes per bin
#define BIN_SHIFT 6
#define BIN_NODES 64
#define NBINS ((N_NODES + BIN_NODES - 1) >> BIN_SHIFT)   // 1563
#define BIN_CAP 1152    // bin total ~Poisson(640), 20 sigma headroom

// Single-pass chunked partition: 256 chunks, fixed per-(chunk,bin) cells.
// Cell = 16 ints = one 64B line: [0]=count, [1..15]=packed entries.
// lambda = 2.5 per cell; P(Poisson(2.5) >= 16) ~ 1e-8 -> ~0.004 expected
// overflows over all 400k cells: never happens in practice.
#define NCHUNK 256
#define CHUNK_E ((N_EDGES + NCHUNK - 1) / NCHUNK)   // 3907
#define CELL 16
#define CCAP_E 15

// ---------------------------------------------------------------------------
// Workspace layout (ints):
//   bucket [NCHUNK][NBINS][CELL]   ~25.6 MB
//   emb16  [N_NODES*D_FEAT] __half ~12.8 MB (3.2M ints)
// ---------------------------------------------------------------------------
#define WS_BUCKET_INTS ((size_t)NCHUNK * NBINS * CELL)
#define WS_EMB16       WS_BUCKET_INTS
#define WS_NEEDED      ((WS_BUCKET_INTS + (size_t)N_NODES * D_FEAT / 2) * sizeof(int))

// K1 (fused): blocks 0..255 partition edges into cells; blocks 256..511
// convert emb f32 -> fp16 (streams concurrently).
__global__ __launch_bounds__(1024) void prep_kernel(const float* __restrict__ emb,
                                                    const int* __restrict__ src,
                                                    const int* __restrict__ dst,
                                                    int* __restrict__ ws) {
    int tid = threadIdx.x;
    if (blockIdx.x < NCHUNK) {
        __shared__ int h[NBINS];
        for (int j = tid; j < NBINS; j += 1024) h[j] = 0;
        __syncthreads();
        int c  = blockIdx.x;
        int e0 = c * CHUNK_E, e1 = min(N_EDGES, e0 + CHUNK_E);
        int* __restrict__ cells = ws + (size_t)c * NBINS * CELL;
        for (int e = e0 + tid; e < e1; e += 1024) {
            int d = dst[e], s = src[e];
            int bin = d >> BIN_SHIFT;
            int slot = atomicAdd(&h[bin], 1);            // LDS atomic
            if (slot < CCAP_E)
                cells[bin * CELL + 1 + slot] = ((d & (BIN_NODES - 1)) << 17) | s;
        }
        __syncthreads();
        for (int j = tid; j < NBINS; j += 1024)
            cells[j * CELL] = min(h[j], CCAP_E);
    } else {
        // f32 -> fp16 conversion: 1.6M float4 -> 2x half2
        __half2* __restrict__ e16 = (__half2*)(ws + WS_EMB16);
        const float4* __restrict__ e32 = (const float4*)emb;
        const int total4 = N_NODES * D_FEAT / 4;         // 1,600,000
        int start = (blockIdx.x - NCHUNK) * 1024 + tid;
        for (int i = start; i < total4; i += NCHUNK * 1024) {
            float4 v = e32[i];
            e16[2 * i]     = __floats2half2_rn(v.x, v.y);
            e16[2 * i + 1] = __floats2half2_rn(v.z, v.w);
        }
    }
}

// K2: per-bin gather (fp16 rows). Stage the bin's 256 cells into LDS via a
// bump allocator (+histogram), counting-sort by local dst, then gather:
// 8 waves x 8 nodes; 8-lane group per row, lane loads 16B (8 halves) ->
// f32 accumulate; 3-step shfl_xor reduce across 8 edge subgroups.
__global__ __launch_bounds__(512) void fused_gather_kernel(const int* __restrict__ ws,
                                                           float* __restrict__ out) {
    __shared__ int s_edges[BIN_CAP];
    __shared__ int s_sorted[BIN_CAP];
    __shared__ int s_rcnt[NCHUNK];
    __shared__ int s_roff[NCHUNK];
    __shared__ int s_hist[BIN_NODES];
    __shared__ int s_off[BIN_NODES];
    __shared__ int s_cur[BIN_NODES];
    __shared__ int s_alloc;

    const char* __restrict__ emb16 = (const char*)(ws + WS_EMB16);
    int b   = blockIdx.x;
    int tid = threadIdx.x;

    if (tid < BIN_NODES) s_hist[tid] = 0;
    if (tid == 0) s_alloc = 0;
    __syncthreads();

    // phase 1: threads 0..255 read their cell's count, bump-allocate
    if (tid < NCHUNK) {
        int cnt = ws[((size_t)tid * NBINS + b) * CELL];
        s_rcnt[tid] = cnt;
        s_roff[tid] = atomicAdd(&s_alloc, cnt);
    }
    __syncthreads();
    int total = s_alloc;
    if (total > BIN_CAP) total = BIN_CAP;

    // phase 2: 2 threads per cell copy entries + histogram
    {
        int g = tid >> 1, li = tid & 1;
        int cg = s_rcnt[g], og = s_roff[g];
        const int* __restrict__ cell = ws + ((size_t)g * NBINS + b) * CELL + 1;
        for (int i = li; i < cg; i += 2) {
            int o = og + i;
            if (o < BIN_CAP) {
                int p = cell[i];
                s_edges[o] = p;
                atomicAdd(&s_hist[p >> 17], 1);
            }
        }
    }
    __syncthreads();

    // scan 64 hist entries with wave 0
    if (tid < 64) {
        int v = s_hist[tid];
        int incl = v;
        #pragma unroll
        for (int o = 1; o < 64; o <<= 1) {
            int t = __shfl_up(incl, o);
            if (tid >= o) incl += t;
        }
        s_off[tid] = incl - v;
        s_cur[tid] = incl - v;
    }
    __syncthreads();

    // counting-sort scatter within LDS
    for (int i = tid; i < total; i += 512) {
        int p = s_edges[i];
        s_sorted[atomicAdd(&s_cur[p >> 17], 1)] = p & 0x1FFFF;
    }
    __syncthreads();

    // gather: 8 waves x 8 nodes; sub = edge slot (0..7), f8 = 16B index (0..7)
    int wave = tid >> 6, lane = tid & 63;
    int sub  = lane >> 3;
    int f8   = lane & 7;
    const int fb = f8 << 4;          // byte offset of this lane's 16B in a row

    #pragma unroll
    for (int ln0 = 0; ln0 < 8; ++ln0) {
        int ln  = wave * 8 + ln0;
        int deg = s_hist[ln];
        int off = s_off[ln];

        float4 accLo = make_float4(0.f, 0.f, 0.f, 0.f);
        float4 accHi = make_float4(0.f, 0.f, 0.f, 0.f);

        int i = sub;
        // main (deg > 8+sub): 2 rows in flight per group
        for (; i + 8 < deg; i += 16) {
            uint4 u0 = *(const uint4*)(emb16 + ((size_t)s_sorted[off + i]     << 7) + fb);
            uint4 u1 = *(const uint4*)(emb16 + ((size_t)s_sorted[off + i + 8] << 7) + fb);
            float2 f;
            f = __half22float2(*(__half2*)&u0.x); accLo.x += f.x; accLo.y += f.y;
            f = __half22float2(*(__half2*)&u0.y); accLo.z += f.x; accLo.w += f.y;
            f = __half22float2(*(__half2*)&u0.z); accHi.x += f.x; accHi.y += f.y;
            f = __half22float2(*(__half2*)&u0.w); accHi.z += f.x; accHi.w += f.y;
            f = __half22float2(*(__half2*)&u1.x); accLo.x += f.x; accLo.y += f.y;
            f = __half22float2(*(__half2*)&u1.y); accLo.z += f.x; accLo.w += f.y;
            f = __half22float2(*(__half2*)&u1.z); accHi.x += f.x; accHi.y += f.y;
            f = __half22float2(*(__half2*)&u1.w); accHi.z += f.x; accHi.w += f.y;
        }
        // tail: one guarded load
        if (i < deg) {
            uint4 u0 = *(const uint4*)(emb16 + ((size_t)s_sorted[off + i] << 7) + fb);
            float2 f;
            f = __half22float2(*(__half2*)&u0.x); accLo.x += f.x; accLo.y += f.y;
            f = __half22float2(*(__half2*)&u0.y); accLo.z += f.x; accLo.w += f.y;
            f = __half22float2(*(__half2*)&u0.z); accHi.x += f.x; accHi.y += f.y;
            f = __half22float2(*(__half2*)&u0.w); accHi.z += f.x; accHi.w += f.y;
        }

        // reduce across the 8 edge subgroups (lanes l ^ {8,16,32})
        #pragma unroll
        for (int m = 8; m < 64; m <<= 1) {
            accLo.x += __shfl_xor(accLo.x, m);
            accLo.y += __shfl_xor(accLo.y, m);
            accLo.z += __shfl_xor(accLo.z, m);
            accLo.w += __shfl_xor(accLo.w, m);
            accHi.x += __shfl_xor(accHi.x, m);
            accHi.y += __shfl_xor(accHi.y, m);
            accHi.z += __shfl_xor(accHi.z, m);
            accHi.w += __shfl_xor(accHi.w, m);
        }

        if (sub == 0) {
            int node = (b << BIN_SHIFT) + ln;
            if (node < N_NODES) {
                float inv = 1.0f / (float)max(deg, 1);
                accLo.x *= inv; accLo.y *= inv; accLo.z *= inv; accLo.w *= inv;
                accHi.x *= inv; accHi.y *= inv; accHi.z *= inv; accHi.w *= inv;
                float* orow = out + (size_t)node * D_FEAT + f8 * 8;
                *(float4*)(orow)     = accLo;
                *(float4*)(orow + 4) = accHi;
            }
        }
    }
}

// ======================= Fallback (R1 atomic path) =========================

__global__ void gcn_zero_kernel(float* __restrict__ out, float* __restrict__ counts) {
    int stride = gridDim.x * blockDim.x;
    int i = blockIdx.x * blockDim.x + threadIdx.x;
    const int total = N_NODES * D_FEAT;
    for (int idx = i; idx < total; idx += stride) out[idx] = 0.0f;
    for (int idx = i; idx < N_NODES; idx += stride) counts[idx] = 0.0f;
}

__global__ void gcn_scatter_kernel(const float* __restrict__ emb,
                                   const int* __restrict__ src,
                                   const int* __restrict__ dst,
                                   float* __restrict__ out,
                                   float* __restrict__ counts) {
    int gid  = blockIdx.x * blockDim.x + threadIdx.x;
    int edge = gid >> 6;
    int lane = gid & 63;
    if (edge >= N_EDGES) return;
    int s = src[edge];
    int d = dst[edge];
    float v = emb[(size_t)s * D_FEAT + lane];
    atomicAdd(&out[(size_t)d * D_FEAT + lane], v);
    if (lane == 0) atomicAdd(&counts[d], 1.0f);
}

__global__ void gcn_norm_kernel(float* __restrict__ out,
                                const float* __restrict__ counts) {
    int i = blockIdx.x * blockDim.x + threadIdx.x;
    if (i >= N_NODES * D_FEAT) return;
    int n = i >> 6;
    float c = counts[n];
    out[i] *= (1.0f / fmaxf(c, 1.0f));
}

// ===========================================================================

extern "C" void kernel_launch(void* const* d_in, const int* in_sizes, int n_in,
                              void* d_out, int out_size, void* d_ws, size_t ws_size,
                              hipStream_t stream) {
    const float* emb = (const float*)d_in[0];
    const int*   src = (const int*)d_in[1];
    const int*   dst = (const int*)d_in[2];
    float* out = (float*)d_out;

    if (ws_size >= WS_NEEDED) {
        int* ws = (int*)d_ws;
        prep_kernel<<<2 * NCHUNK, 1024, 0, stream>>>(emb, src, dst, ws);
        fused_gather_kernel<<<NBINS, 512, 0, stream>>>(ws, out);
    } else {
        float* counts = (float*)d_ws;
        gcn_zero_kernel<<<2048, 256, 0, stream>>>(out, counts);
        const int scatter_blocks = (N_EDGES * 64) / 256;
        gcn_scatter_kernel<<<scatter_blocks, 256, 0, stream>>>(emb, src, dst, out, counts);
        const int norm_blocks = (N_NODES * D_FEAT + 255) / 256;
        gcn_norm_kernel<<<norm_blocks, 256, 0, stream>>>(out, counts);
    }
}

// Round 17
// 56.173 us; speedup vs baseline: 1.2935x; 1.2935x over previous
//
#include <hip/hip_runtime.h>
#include <hip/hip_fp16.h>

#define N_NODES 100000
#define N_EDGES 1000000
#define D_FEAT  64

// Binning: 64 consecutive dst nodes per bin
#define BIN_SHIFT 6
#define BIN_NODES 64
#define NBINS ((N_NODES + BIN_NODES - 1) >> BIN_SHIFT)   // 1563
#define BIN_CAP 1152    // bin total ~Poisson(640), 20 sigma headroom

// Dense single-pass partition: 128 chunks; each block LDS-sorts its 7813
// edges by bin and writes ONE dense run region (no cells, no holes).
#define NCHUNK 128
#define CHUNK_E ((N_EDGES + NCHUNK - 1) / NCHUNK)   // 7813
#define PCHUNK 7936                                  // padded region (ints)

// ---------------------------------------------------------------------------
// Workspace layout (ints):
//   CNT    u16 [NBINS][NCHUNK]  per-(bin,chunk) run length   (400 KB)
//   PF     u16 [NBINS][NCHUNK]  exclusive prefix within chunk (400 KB)
//   bucket [NCHUNK][PCHUNK]     packed (local_dst<<17)|src, dense runs (4 MB)
//   emb16  [N_NODES*D_FEAT] __half                           (12.8 MB)
// ---------------------------------------------------------------------------
#define WS_CNT    0
#define WS_PF     (NBINS * NCHUNK / 2)
#define WS_BUCKET (NBINS * NCHUNK)
#define WS_EMB16  (WS_BUCKET + NCHUNK * PCHUNK)
#define WS_NEEDED ((size_t)(WS_EMB16 + (size_t)N_NODES * D_FEAT / 2) * sizeof(int))

// K1 (fused): blocks 0..127 dense-partition edges; blocks 128..255 convert
// emb f32 -> fp16 (streams concurrently on the other CUs).
__global__ __launch_bounds__(1024) void prep_kernel(const float* __restrict__ emb,
                                                    const int* __restrict__ src,
                                                    const int* __restrict__ dst,
                                                    int* __restrict__ ws) {
    int tid = threadIdx.x;
    if (blockIdx.x < NCHUNK) {
        __shared__ int h[NBINS];                 // hist -> prefix -> cursor
        __shared__ unsigned short s_bin[CHUNK_E];
        __shared__ int s_pack[CHUNK_E];
        for (int j = tid; j < NBINS; j += 1024) h[j] = 0;
        __syncthreads();
        int c  = blockIdx.x;
        int e0 = c * CHUNK_E;
        int n  = min(N_EDGES, e0 + CHUNK_E) - e0;
        for (int i = tid; i < n; i += 1024) {
            int d = dst[e0 + i], s = src[e0 + i];
            int bin = d >> BIN_SHIFT;
            s_bin[i]  = (unsigned short)bin;
            s_pack[i] = ((d & (BIN_NODES - 1)) << 17) | s;
            atomicAdd(&h[bin], 1);               // LDS atomic
        }
        __syncthreads();
        // write run lengths (transposed u16: gather reads contiguous rows)
        unsigned short* CNT = (unsigned short*)(ws + WS_CNT);
        for (int j = tid; j < NBINS; j += 1024)
            CNT[j * NCHUNK + c] = (unsigned short)h[j];
        __syncthreads();
        // wave 0: exclusive scan of h in place
        if (tid < 64) {
            int lane = tid, carry = 0;
            for (int cb = 0; cb < NBINS; cb += 64) {
                int idx = cb + lane;
                int v = (idx < NBINS) ? h[idx] : 0;
                int incl = v;
                #pragma unroll
                for (int o = 1; o < 64; o <<= 1) {
                    int t = __shfl_up(incl, o);
                    if (lane >= o) incl += t;
                }
                if (idx < NBINS) h[idx] = carry + incl - v;
                carry += __shfl(incl, 63);
            }
        }
        __syncthreads();
        unsigned short* PF = (unsigned short*)(ws + WS_PF);
        for (int j = tid; j < NBINS; j += 1024)
            PF[j * NCHUNK + c] = (unsigned short)h[j];
        __syncthreads();
        // placement: h doubles as per-bin cursor; dense coalescing writes
        int* __restrict__ run = ws + WS_BUCKET + c * PCHUNK;
        for (int i = tid; i < n; i += 1024) {
            int slot = atomicAdd(&h[s_bin[i]], 1);
            run[slot] = s_pack[i];
        }
    } else {
        // f32 -> fp16 conversion: 1.6M float4 -> 2x half2
        __half2* __restrict__ e16 = (__half2*)(ws + WS_EMB16);
        const float4* __restrict__ e32 = (const float4*)emb;
        const int total4 = N_NODES * D_FEAT / 4;         // 1,600,000
        int start = (blockIdx.x - NCHUNK) * 1024 + tid;
        for (int i = start; i < total4; i += NCHUNK * 1024) {
            float4 v = e32[i];
            e16[2 * i]     = __floats2half2_rn(v.x, v.y);
            e16[2 * i + 1] = __floats2half2_rn(v.z, v.w);
        }
    }
}

// K2: per-bin gather (fp16 rows) — R15's proven structure. Stage the bin's
// 128 dense runs into LDS via bump allocator (+histogram), counting-sort by
// local dst, then gather: 8 waves x 8 nodes in PAIRS; 16-lane group per row,
// lane loads 8B (4 halves) -> f32 accumulate; 6 guarded tail loads in
// flight; shfl_xor reduce across 4 edge subgroups.
__global__ __launch_bounds__(512) void fused_gather_kernel(const int* __restrict__ ws,
                                                           float* __restrict__ out) {
    __shared__ int s_edges[BIN_CAP];
    __shared__ int s_sorted[BIN_CAP];
    __shared__ int s_rcnt[NCHUNK];
    __shared__ int s_roff[NCHUNK];
    __shared__ int s_rbase[NCHUNK];
    __shared__ int s_hist[BIN_NODES];
    __shared__ int s_off[BIN_NODES];
    __shared__ int s_cur[BIN_NODES];
    __shared__ int s_alloc;

    const char* __restrict__ emb16 = (const char*)(ws + WS_EMB16);
    int b   = blockIdx.x;
    int tid = threadIdx.x;

    if (tid < BIN_NODES) s_hist[tid] = 0;
    if (tid == 0) s_alloc = 0;
    __syncthreads();

    // phase 1: threads 0..127 read run length + prefix (coalesced u16 rows)
    if (tid < NCHUNK) {
        const unsigned short* CNT = (const unsigned short*)(ws + WS_CNT);
        const unsigned short* PF  = (const unsigned short*)(ws + WS_PF);
        int cnt = (int)CNT[b * NCHUNK + tid];
        int pf  = (int)PF[b * NCHUNK + tid];
        s_rcnt[tid]  = cnt;
        s_rbase[tid] = tid * PCHUNK + pf;
        s_roff[tid]  = atomicAdd(&s_alloc, cnt);
    }
    __syncthreads();
    int total = s_alloc;
    if (total > BIN_CAP) total = BIN_CAP;

    // phase 2: 4 threads per run copy entries + histogram
    {
        int g = tid >> 2, li = tid & 3;
        int cg = s_rcnt[g], og = s_roff[g];
        const int* __restrict__ run = ws + WS_BUCKET + s_rbase[g];
        for (int i = li; i < cg; i += 4) {
            int o = og + i;
            if (o < BIN_CAP) {
                int p = run[i];
                s_edges[o] = p;
                atomicAdd(&s_hist[p >> 17], 1);
            }
        }
    }
    __syncthreads();

    // scan 64 hist entries with wave 0
    if (tid < 64) {
        int v = s_hist[tid];
        int incl = v;
        #pragma unroll
        for (int o = 1; o < 64; o <<= 1) {
            int t = __shfl_up(incl, o);
            if (tid >= o) incl += t;
        }
        s_off[tid] = incl - v;
        s_cur[tid] = incl - v;
    }
    __syncthreads();

    // counting-sort scatter within LDS
    for (int i = tid; i < total; i += 512) {
        int p = s_edges[i];
        s_sorted[atomicAdd(&s_cur[p >> 17], 1)] = p & 0x1FFFF;
    }
    __syncthreads();

    // gather: 8 waves x 8 nodes in 4 pairs; sub = edge slot, fq = 8B index
    int wave = tid >> 6, lane = tid & 63;
    int sub  = lane >> 4;
    int fq   = lane & 15;
    const int fb = fq << 3;          // byte offset of this lane's 8B in a row

    #pragma unroll
    for (int pr = 0; pr < 4; ++pr) {
        int lnA = wave * 8 + pr * 2;
        int lnB = lnA + 1;
        int degA = s_hist[lnA], offA = s_off[lnA];
        int degB = s_hist[lnB], offB = s_off[lnB];

        float4 accA = make_float4(0.f, 0.f, 0.f, 0.f);
        float4 accB = make_float4(0.f, 0.f, 0.f, 0.f);

        int iA = sub, iB = sub;
        // main loops (deg > 15; rare): 4 rows in flight
        for (; iA + 12 < degA; iA += 16) {
            uint2 u0 = *(const uint2*)(emb16 + ((size_t)s_sorted[offA + iA]      << 7) + fb);
            uint2 u1 = *(const uint2*)(emb16 + ((size_t)s_sorted[offA + iA + 4]  << 7) + fb);
            uint2 u2 = *(const uint2*)(emb16 + ((size_t)s_sorted[offA + iA + 8]  << 7) + fb);
            uint2 u3 = *(const uint2*)(emb16 + ((size_t)s_sorted[offA + iA + 12] << 7) + fb);
            float2 f;
            f = __half22float2(*(__half2*)&u0.x); accA.x += f.x; accA.y += f.y;
            f = __half22float2(*(__half2*)&u0.y); accA.z += f.x; accA.w += f.y;
            f = __half22float2(*(__half2*)&u1.x); accA.x += f.x; accA.y += f.y;
            f = __half22float2(*(__half2*)&u1.y); accA.z += f.x; accA.w += f.y;
            f = __half22float2(*(__half2*)&u2.x); accA.x += f.x; accA.y += f.y;
            f = __half22float2(*(__half2*)&u2.y); accA.z += f.x; accA.w += f.y;
            f = __half22float2(*(__half2*)&u3.x); accA.x += f.x; accA.y += f.y;
            f = __half22float2(*(__half2*)&u3.y); accA.z += f.x; accA.w += f.y;
        }
        for (; iB + 12 < degB; iB += 16) {
            uint2 u0 = *(const uint2*)(emb16 + ((size_t)s_sorted[offB + iB]      << 7) + fb);
            uint2 u1 = *(const uint2*)(emb16 + ((size_t)s_sorted[offB + iB + 4]  << 7) + fb);
            uint2 u2 = *(const uint2*)(emb16 + ((size_t)s_sorted[offB + iB + 8]  << 7) + fb);
            uint2 u3 = *(const uint2*)(emb16 + ((size_t)s_sorted[offB + iB + 12] << 7) + fb);
            float2 f;
            f = __half22float2(*(__half2*)&u0.x); accB.x += f.x; accB.y += f.y;
            f = __half22float2(*(__half2*)&u0.y); accB.z += f.x; accB.w += f.y;
            f = __half22float2(*(__half2*)&u1.x); accB.x += f.x; accB.y += f.y;
            f = __half22float2(*(__half2*)&u1.y); accB.z += f.x; accB.w += f.y;
            f = __half22float2(*(__half2*)&u2.x); accB.x += f.x; accB.y += f.y;
            f = __half22float2(*(__half2*)&u2.y); accB.z += f.x; accB.w += f.y;
            f = __half22float2(*(__half2*)&u3.x); accB.x += f.x; accB.y += f.y;
            f = __half22float2(*(__half2*)&u3.y); accB.z += f.x; accB.w += f.y;
        }
        // tails: up to 6 independent guarded loads, all issued before use
        {
            uint2 a0 = make_uint2(0u, 0u), a1 = a0, a2 = a0;
            uint2 b0 = a0, b1 = a0, b2 = a0;
            if (iA < degA)     a0 = *(const uint2*)(emb16 + ((size_t)s_sorted[offA + iA]     << 7) + fb);
            if (iA + 4 < degA) a1 = *(const uint2*)(emb16 + ((size_t)s_sorted[offA + iA + 4] << 7) + fb);
            if (iA + 8 < degA) a2 = *(const uint2*)(emb16 + ((size_t)s_sorted[offA + iA + 8] << 7) + fb);
            if (iB < degB)     b0 = *(const uint2*)(emb16 + ((size_t)s_sorted[offB + iB]     << 7) + fb);
            if (iB + 4 < degB) b1 = *(const uint2*)(emb16 + ((size_t)s_sorted[offB + iB + 4] << 7) + fb);
            if (iB + 8 < degB) b2 = *(const uint2*)(emb16 + ((size_t)s_sorted[offB + iB + 8] << 7) + fb);
            float2 f;
            f = __half22float2(*(__half2*)&a0.x); accA.x += f.x; accA.y += f.y;
            f = __half22float2(*(__half2*)&a0.y); accA.z += f.x; accA.w += f.y;
            f = __half22float2(*(__half2*)&a1.x); accA.x += f.x; accA.y += f.y;
            f = __half22float2(*(__half2*)&a1.y); accA.z += f.x; accA.w += f.y;
            f = __half22float2(*(__half2*)&a2.x); accA.x += f.x; accA.y += f.y;
            f = __half22float2(*(__half2*)&a2.y); accA.z += f.x; accA.w += f.y;
            f = __half22float2(*(__half2*)&b0.x); accB.x += f.x; accB.y += f.y;
            f = __half22float2(*(__half2*)&b0.y); accB.z += f.x; accB.w += f.y;
            f = __half22float2(*(__half2*)&b1.x); accB.x += f.x; accB.y += f.y;
            f = __half22float2(*(__half2*)&b1.y); accB.z += f.x; accB.w += f.y;
            f = __half22float2(*(__half2*)&b2.x); accB.x += f.x; accB.y += f.y;
            f = __half22float2(*(__half2*)&b2.y); accB.z += f.x; accB.w += f.y;
        }

        // reduce both across the 4 edge subgroups (independent chains)
        #pragma unroll
        for (int m = 16; m < 64; m <<= 1) {
            accA.x += __shfl_xor(accA.x, m);  accB.x += __shfl_xor(accB.x, m);
            accA.y += __shfl_xor(accA.y, m);  accB.y += __shfl_xor(accB.y, m);
            accA.z += __shfl_xor(accA.z, m);  accB.z += __shfl_xor(accB.z, m);
            accA.w += __shfl_xor(accA.w, m);  accB.w += __shfl_xor(accB.w, m);
        }

        if (sub == 0) {
            int nodeA = (b << BIN_SHIFT) + lnA;
            int nodeB = (b << BIN_SHIFT) + lnB;
            float invA = 1.0f / (float)max(degA, 1);
            float invB = 1.0f / (float)max(degB, 1);
            accA.x *= invA; accA.y *= invA; accA.z *= invA; accA.w *= invA;
            accB.x *= invB; accB.y *= invB; accB.z *= invB; accB.w *= invB;
            if (nodeA < N_NODES)
                *(float4*)(out + (size_t)nodeA * D_FEAT + fq * 4) = accA;
            if (nodeB < N_NODES)
                *(float4*)(out + (size_t)nodeB * D_FEAT + fq * 4) = accB;
        }
    }
}

// ======================= Fallback (R1 atomic path) =========================

__global__ void gcn_zero_kernel(float* __restrict__ out, float* __restrict__ counts) {
    int stride = gridDim.x * blockDim.x;
    int i = blockIdx.x * blockDim.x + threadIdx.x;
    const int total = N_NODES * D_FEAT;
    for (int idx = i; idx < total; idx += stride) out[idx] = 0.0f;
    for (int idx = i; idx < N_NODES; idx += stride) counts[idx] = 0.0f;
}

__global__ void gcn_scatter_kernel(const float* __restrict__ emb,
                                   const int* __restrict__ src,
                                   const int* __restrict__ dst,
                                   float* __restrict__ out,
                                   float* __restrict__ counts) {
    int gid  = blockIdx.x * blockDim.x + threadIdx.x;
    int edge = gid >> 6;
    int lane = gid & 63;
    if (edge >= N_EDGES) return;
    int s = src[edge];
    int d = dst[edge];
    float v = emb[(size_t)s * D_FEAT + lane];
    atomicAdd(&out[(size_t)d * D_FEAT + lane], v);
    if (lane == 0) atomicAdd(&counts[d], 1.0f);
}

__global__ void gcn_norm_kernel(float* __restrict__ out,
                                const float* __restrict__ counts) {
    int i = blockIdx.x * blockDim.x + threadIdx.x;
    if (i >= N_NODES * D_FEAT) return;
    int n = i >> 6;
    float c = counts[n];
    out[i] *= (1.0f / fmaxf(c, 1.0f));
}

// ===========================================================================

extern "C" void kernel_launch(void* const* d_in, const int* in_sizes, int n_in,
                              void* d_out, int out_size, void* d_ws, size_t ws_size,
                              hipStream_t stream) {
    const float* emb = (const float*)d_in[0];
    const int*   src = (const int*)d_in[1];
    const int*   dst = (const int*)d_in[2];
    float* out = (float*)d_out;

    if (ws_size >= WS_NEEDED) {
        int* ws = (int*)d_ws;
        prep_kernel<<<2 * NCHUNK, 1024, 0, stream>>>(emb, src, dst, ws);
        fused_gather_kernel<<<NBINS, 512, 0, stream>>>(ws, out);
    } else {
        float* counts = (float*)d_ws;
        gcn_zero_kernel<<<2048, 256, 0, stream>>>(out, counts);
        const int scatter_blocks = (N_EDGES * 64) / 256;
        gcn_scatter_kernel<<<scatter_blocks, 256, 0, stream>>>(emb, src, dst, out, counts);
        const int norm_blocks = (N_NODES * D_FEAT + 255) / 256;
        gcn_norm_kernel<<<norm_blocks, 256, 0, stream>>>(out, counts);
    }
}